// Round 9
// baseline (269.549 us; speedup 1.0000x reference)
//
#include <hip/hip_runtime.h>

// ---------------------------------------------------------------------------
// self_transformer: q=xW1^T+b1, k=xW2^T+b2, v=xW3^T+b3,
//                   attn=softmax((k q^T)/sqrt(D)), out=attn@v
// N=4096, D=1024. All matmuls via mfma_f32_16x16x32_bf16, fp32 accum.
// R9 = R8 minus the XCD supertile swizzle (measured -45% on the E-gemm:
//     104 vs 58-72 us; FETCH dropped but kernel is latency-bound, and the
//     remap destroyed natural dispatch-order A-panel sharing). Keeps:
//     dense q/k/v (lda 1024), 128x96 qkv-gemm, 128x64 split-K=2 out-gemm
//     with fp32 partials, fused rowsum+add+divide reduce.
// ---------------------------------------------------------------------------

typedef short bf16x8 __attribute__((ext_vector_type(8)));  // 8 bf16 = 4 VGPRs
typedef float f32x4  __attribute__((ext_vector_type(4)));

__device__ __forceinline__ short f2bf(float f) {
    unsigned u = __builtin_bit_cast(unsigned, f);
    u += 0x7FFFu + ((u >> 16) & 1u);   // round-to-nearest-even
    return (short)(u >> 16);
}
__device__ __forceinline__ float bf2f(short s) {
    return __builtin_bit_cast(float, (unsigned)((unsigned short)s) << 16);
}

__device__ __forceinline__ void gld_lds16(const short* g, short* l) {
    __builtin_amdgcn_global_load_lds(
        (const __attribute__((address_space(1))) void*)g,
        (__attribute__((address_space(3))) void*)l, 16, 0, 0);
}

// BT GEMM: C[a][b] = scale * sum_i A[a*lda+i] * B[b*ldb+i]  (+ per-col bias)
// cmode: 1 = fp32 store at split-K offset z*zstride (A/B k-offset z*K)
//        2 = bf16 exp() store (dense, ldc)
//        4 = bf16 qkv-split store: dst[(col>>10)*4194304 + row*1024 + (col&1023)]
// LDS: BK=64, XOR-swizzled 16B granules: LDS granule p of row r holds global
// granule p^(r&7); fragment read granule (ks*4+quad)^(r&7) -> conflict-free.
template<int BM, int BN>
__global__ __launch_bounds__(256)
void gemm_bt(const short* __restrict__ A, int lda,
             const short* __restrict__ B, int ldb,
             const float* __restrict__ bias,
             void* __restrict__ Cout, int ldc, int cmode, float scale,
             int K, size_t zstride)
{
    constexpr int NT = BN / 32;                 // MFMA col-tiles per wave
    __shared__ __align__(16) short As[BM * 64];
    __shared__ __align__(16) short Bs[BN * 64];

    const int tid  = threadIdx.x;
    const int lane = tid & 63;
    const int wave = tid >> 6;
    const int wm   = (wave >> 1) * 64;          // wave row offset
    const int wn   = (wave & 1) * (BN / 2);     // wave col offset
    const int quad = lane >> 4;
    const int l16  = lane & 15;
    const size_t bm0 = (size_t)blockIdx.y * BM;
    const size_t bn0 = (size_t)blockIdx.x * BN;
    const int koff = blockIdx.z * K;

    f32x4 acc[4][NT] = {};

    // staging lane decode: chunk row + swizzled global granule
    const int srow = lane >> 3;                        // 0..7
    const int scol = ((lane & 7) ^ srow) << 3;         // swizzled elem col
    const short* Ag = A + (bm0 + srow) * (size_t)lda + koff + scol;
    const short* Bg = B + (bn0 + srow) * (size_t)ldb + koff + scol;

    for (int k0 = 0; k0 < K; k0 += 64) {
#pragma unroll
        for (int cc = 0; cc < BM / 8; cc += 4) {
            const int c = cc + wave;
            gld_lds16(Ag + (size_t)c * 8 * lda + k0, &As[c * 512]);
        }
#pragma unroll
        for (int cc = 0; cc < BN / 8; cc += 4) {
            const int c = cc + wave;
            gld_lds16(Bg + (size_t)c * 8 * ldb + k0, &Bs[c * 512]);
        }
        __syncthreads();

#pragma unroll
        for (int ks = 0; ks < 2; ks++) {
            const int sw = (ks << 2) + quad;
            bf16x8 af[4], bfr[NT];
#pragma unroll
            for (int mt = 0; mt < 4; mt++) {
                const int r = wm + mt * 16 + l16;
                af[mt] = *(const bf16x8*)(&As[r * 64 + ((sw ^ (r & 7)) << 3)]);
            }
#pragma unroll
            for (int nt = 0; nt < NT; nt++) {
                const int r = wn + nt * 16 + l16;
                bfr[nt] = *(const bf16x8*)(&Bs[r * 64 + ((sw ^ (r & 7)) << 3)]);
            }
#pragma unroll
            for (int mt = 0; mt < 4; mt++)
#pragma unroll
                for (int nt = 0; nt < NT; nt++)
                    acc[mt][nt] = __builtin_amdgcn_mfma_f32_16x16x32_bf16(
                        af[mt], bfr[nt], acc[mt][nt], 0, 0, 0);
        }
        __syncthreads();
    }

    // epilogue: C/D layout col=lane&15, row=quad*4+reg
    float* Cf = (float*)Cout + blockIdx.z * zstride;
    short* Cs = (short*)Cout;
#pragma unroll
    for (int mt = 0; mt < 4; mt++) {
#pragma unroll
        for (int nt = 0; nt < NT; nt++) {
            const size_t col = bn0 + wn + nt * 16 + l16;
            const float bc = bias ? bias[col] : 0.0f;
#pragma unroll
            for (int r = 0; r < 4; r++) {
                const size_t row = bm0 + wm + mt * 16 + quad * 4 + r;
                const float v = acc[mt][nt][r] * scale + bc;
                if (cmode == 1) {
                    Cf[row * (size_t)ldc + col] = v;
                } else if (cmode == 2) {
                    Cs[row * (size_t)ldc + col] = f2bf(__expf(v));
                } else {  // 4: qkv split store (q,k,v contiguous, 4M shorts each)
                    Cs[(col >> 10) * (size_t)4194304 + row * 1024 + (col & 1023)]
                        = f2bf(v);
                }
            }
        }
    }
}

// 64x64 LDS-tiled transpose: vt[d][n] = v[n*1024 + d]
__global__ __launch_bounds__(256)
void transpose_v(const short* __restrict__ v, short* __restrict__ vt)
{
    __shared__ short sh[64][72];   // +8 pad
    const int n0 = blockIdx.x * 64, d0 = blockIdx.y * 64;
    const int t = threadIdx.x;
    const int r = t >> 2, c = (t & 3) << 4;

    const short* src = v + (size_t)(n0 + r) * 1024 + d0 + c;
    *(int4*)(&sh[r][c])     = *(const int4*)(src);
    *(int4*)(&sh[r][c + 8]) = *(const int4*)(src + 8);
    __syncthreads();

    short tmp[16];
#pragma unroll
    for (int j = 0; j < 16; j++) tmp[j] = sh[c + j][r];
    short* dst = vt + (size_t)(d0 + r) * 4096 + n0 + c;
    *(int4*)(dst)     = *(const int4*)(tmp);
    *(int4*)(dst + 8) = *(const int4*)(tmp + 8);
}

// One block per output row n: rsum = sum(E[n,:]);
// out[n,:] = (p0[n,:] + p1[n,:]) / rsum   (fp32 partials)
__global__ __launch_bounds__(256)
void reduce2div(const short* __restrict__ E, const float* __restrict__ outp,
                float* __restrict__ out)
{
    const int row = blockIdx.x;
    const int t = threadIdx.x;
    const int wave = t >> 6, lane = t & 63;

    const short* e = E + (size_t)row * 4096 + (t << 4);
    short sh[16];
    *(int4*)(sh)     = *(const int4*)(e);
    *(int4*)(sh + 8) = *(const int4*)(e + 8);
    float s = 0.0f;
#pragma unroll
    for (int i = 0; i < 16; i++) s += bf2f(sh[i]);
#pragma unroll
    for (int off = 32; off; off >>= 1) s += __shfl_down(s, off);
    __shared__ float red[4];
    if (lane == 0) red[wave] = s;
    __syncthreads();
    const float inv = 1.0f / (red[0] + red[1] + red[2] + red[3]);

    const size_t base = (size_t)row * 1024 + (t << 2);
    const float4 a = *(const float4*)(outp + base);
    const float4 b = *(const float4*)(outp + (size_t)4096 * 1024 + base);
    float4 o;
    o.x = (a.x + b.x) * inv; o.y = (a.y + b.y) * inv;
    o.z = (a.z + b.z) * inv; o.w = (a.w + b.w) * inv;
    *(float4*)(out + base) = o;
}

// single prep: x->xb, W1|W2|W3 -> Wb (element offsets!), bias concat
__global__ __launch_bounds__(256)
void prep(const float* __restrict__ x, const float* __restrict__ W1,
          const float* __restrict__ W2, const float* __restrict__ W3,
          const float* __restrict__ b1, const float* __restrict__ b2,
          const float* __restrict__ b3,
          short* __restrict__ xb, short* __restrict__ Wb,
          float* __restrict__ bcat)
{
    const int i = blockIdx.x * 256 + threadIdx.x;
    const int NX = 1048576;           // 4096*1024/4
    const int NW = 262144;            // 1024*1024/4
    if (i < NX + 3 * NW) {
        const float* src; short* dst; int j;
        if (i < NX)               { src = x;  dst = xb; j = i; }
        else if (i < NX + NW)     { src = W1; dst = Wb; j = i - NX; }
        else if (i < NX + 2 * NW) { src = W2; dst = Wb + 1048576; j = i - NX - NW; }
        else                      { src = W3; dst = Wb + 2097152; j = i - NX - 2 * NW; }
        const float4 f = ((const float4*)src)[j];
        short4 o;
        o.x = f2bf(f.x); o.y = f2bf(f.y); o.z = f2bf(f.z); o.w = f2bf(f.w);
        *(short4*)(dst + (j << 2)) = o;
    } else {
        const int j = i - (NX + 3 * NW);
        if (j < 3072)
            bcat[j] = (j < 1024) ? b1[j] : (j < 2048 ? b2[j - 1024] : b3[j - 2048]);
    }
}

extern "C" void kernel_launch(void* const* d_in, const int* in_sizes, int n_in,
                              void* d_out, int out_size, void* d_ws, size_t ws_size,
                              hipStream_t stream)
{
    const float* x  = (const float*)d_in[0];
    const float* W1 = (const float*)d_in[1];
    const float* b1 = (const float*)d_in[2];
    const float* W2 = (const float*)d_in[3];
    const float* b2 = (const float*)d_in[4];
    const float* W3 = (const float*)d_in[5];
    const float* b3 = (const float*)d_in[6];
    float* out = (float*)d_out;

    const int N = 4096, D = 1024;

    // workspace (peak 78 MB):
    //   vt   [0, 8M)      live: transpose .. out-gemm
    //   E    [8, 40M)     live: E-gemm .. reduce
    //   q    [40, 48M) \
    //   k    [48, 56M)  }  dense lda=1024; dead after E-gemm / transpose
    //   v    [56, 64M) /
    //   xb   [64, 72M)     dead after qkv-gemm
    //   Wb   [72, 78M)     dead after qkv-gemm
    //   bcat [78M, +12K)
    //   outp [40, 72M)     fp32 partials, overlays dead q/k/v/xb
    char* wsb = (char*)d_ws;
    short* vt   = (short*)wsb;
    short* E    = (short*)(wsb + (size_t)8  * 1024 * 1024);
    short* q    = (short*)(wsb + (size_t)40 * 1024 * 1024);  // q,k,v contiguous
    short* k    = (short*)(wsb + (size_t)48 * 1024 * 1024);
    short* v    = (short*)(wsb + (size_t)56 * 1024 * 1024);
    short* xb   = (short*)(wsb + (size_t)64 * 1024 * 1024);
    short* Wb   = (short*)(wsb + (size_t)72 * 1024 * 1024);
    float* bcat = (float*)(wsb + (size_t)78 * 1024 * 1024);
    float* outp = (float*)(wsb + (size_t)40 * 1024 * 1024);

    // 1) prep: casts + bias concat
    prep<<<(1048576 + 3 * 262144 + 3072 + 255) / 256, 256, 0, stream>>>(
        x, W1, W2, W3, b1, b2, b3, xb, Wb, bcat);

    // 2) qkv = x @ [W1;W2;W3]^T + bias -> dense q,k,v  (128x96, grid 1024)
    dim3 gqkv(3 * D / 96, N / 128);
    gemm_bt<128, 96><<<gqkv, 256, 0, stream>>>(xb, D, Wb, D, bcat,
                                               q, 0, 4, 1.0f, D, 0);

    // 3) vt[d][n] = v[n][d]   grid (64,16)=1024 blocks
    dim3 gt(N / 64, D / 64);
    transpose_v<<<gt, 256, 0, stream>>>(v, vt);

    // 4) E = exp((k q^T)/32) bf16  (128x128, grid 32x32, natural order)
    dim3 gs(N / 128, N / 128);
    gemm_bt<128, 128><<<gs, 256, 0, stream>>>(k, D, q, D, nullptr,
                                              E, N, 2, 0.03125f, D, 0);

    // 5) out partials = E @ vt^T, split-K=2, fp32 (128x64, grid (16,32,2))
    dim3 go(D / 64, N / 128, 2);
    gemm_bt<128, 64><<<go, 256, 0, stream>>>(E, N, vt, N, nullptr,
                                             outp, D, 1, 1.0f, N / 2,
                                             (size_t)N * D);

    // 6) out = (p0 + p1) / rowsum(E)
    reduce2div<<<N, 256, 0, stream>>>(E, outp, out);
}

// Round 10
// 260.772 us; speedup vs baseline: 1.0337x; 1.0337x over previous
//
#include <hip/hip_runtime.h>

// ---------------------------------------------------------------------------
// self_transformer: q=xW1^T+b1, k=xW2^T+b2, v=xW3^T+b3,
//                   attn=softmax((k q^T)/sqrt(D)), out=attn@v
// N=4096, D=1024. All matmuls via mfma_f32_16x16x32_bf16, fp32 accum.
// R10: E-gemm operands back to R4's interleaved qk layout (ld 2048; q cols
//     0-1023, k cols 1024-2047). R8/R9's dense q,k buffers sat exactly
//     8 MiB apart with 2 KB power-of-2 row stride -> A/B staging streams
//     hit the SAME L2 sets in lockstep (100 us vs 58-72 interleaved).
//     Keeps: 128x96 qkv-gemm grid 1024, transpose_v, 128x64 split-K=2
//     fp32-partial out-gemm, fused rowsum+add+divide reduce.
// ---------------------------------------------------------------------------

typedef short bf16x8 __attribute__((ext_vector_type(8)));  // 8 bf16 = 4 VGPRs
typedef float f32x4  __attribute__((ext_vector_type(4)));

__device__ __forceinline__ short f2bf(float f) {
    unsigned u = __builtin_bit_cast(unsigned, f);
    u += 0x7FFFu + ((u >> 16) & 1u);   // round-to-nearest-even
    return (short)(u >> 16);
}
__device__ __forceinline__ float bf2f(short s) {
    return __builtin_bit_cast(float, (unsigned)((unsigned short)s) << 16);
}

__device__ __forceinline__ void gld_lds16(const short* g, short* l) {
    __builtin_amdgcn_global_load_lds(
        (const __attribute__((address_space(1))) void*)g,
        (__attribute__((address_space(3))) void*)l, 16, 0, 0);
}

// BT GEMM: C[a][b] = scale * sum_i A[a*lda+i] * B[b*ldb+i]  (+ per-col bias)
// cmode: 1 = fp32 store at split-K offset z*zstride (A/B k-offset z*K)
//        2 = bf16 exp() store (dense, ldc)
//        5 = qkv split: col<2048 -> Cs[row*2048+col] (qk interleaved);
//            col>=2048 -> Vout[row*1024 + col-2048] (dense v)
// LDS: BK=64, XOR-swizzled 16B granules: LDS granule p of row r holds global
// granule p^(r&7); fragment read granule (ks*4+quad)^(r&7) -> conflict-free.
template<int BM, int BN>
__global__ __launch_bounds__(256)
void gemm_bt(const short* __restrict__ A, int lda,
             const short* __restrict__ B, int ldb,
             const float* __restrict__ bias,
             void* __restrict__ Cout, int ldc, int cmode, float scale,
             int K, size_t zstride, short* __restrict__ Vout)
{
    constexpr int NT = BN / 32;                 // MFMA col-tiles per wave
    __shared__ __align__(16) short As[BM * 64];
    __shared__ __align__(16) short Bs[BN * 64];

    const int tid  = threadIdx.x;
    const int lane = tid & 63;
    const int wave = tid >> 6;
    const int wm   = (wave >> 1) * 64;          // wave row offset
    const int wn   = (wave & 1) * (BN / 2);     // wave col offset
    const int quad = lane >> 4;
    const int l16  = lane & 15;
    const size_t bm0 = (size_t)blockIdx.y * BM;
    const size_t bn0 = (size_t)blockIdx.x * BN;
    const int koff = blockIdx.z * K;

    f32x4 acc[4][NT] = {};

    // staging lane decode: chunk row + swizzled global granule
    const int srow = lane >> 3;                        // 0..7
    const int scol = ((lane & 7) ^ srow) << 3;         // swizzled elem col
    const short* Ag = A + (bm0 + srow) * (size_t)lda + koff + scol;
    const short* Bg = B + (bn0 + srow) * (size_t)ldb + koff + scol;

    for (int k0 = 0; k0 < K; k0 += 64) {
#pragma unroll
        for (int cc = 0; cc < BM / 8; cc += 4) {
            const int c = cc + wave;
            gld_lds16(Ag + (size_t)c * 8 * lda + k0, &As[c * 512]);
        }
#pragma unroll
        for (int cc = 0; cc < BN / 8; cc += 4) {
            const int c = cc + wave;
            gld_lds16(Bg + (size_t)c * 8 * ldb + k0, &Bs[c * 512]);
        }
        __syncthreads();

#pragma unroll
        for (int ks = 0; ks < 2; ks++) {
            const int sw = (ks << 2) + quad;
            bf16x8 af[4], bfr[NT];
#pragma unroll
            for (int mt = 0; mt < 4; mt++) {
                const int r = wm + mt * 16 + l16;
                af[mt] = *(const bf16x8*)(&As[r * 64 + ((sw ^ (r & 7)) << 3)]);
            }
#pragma unroll
            for (int nt = 0; nt < NT; nt++) {
                const int r = wn + nt * 16 + l16;
                bfr[nt] = *(const bf16x8*)(&Bs[r * 64 + ((sw ^ (r & 7)) << 3)]);
            }
#pragma unroll
            for (int mt = 0; mt < 4; mt++)
#pragma unroll
                for (int nt = 0; nt < NT; nt++)
                    acc[mt][nt] = __builtin_amdgcn_mfma_f32_16x16x32_bf16(
                        af[mt], bfr[nt], acc[mt][nt], 0, 0, 0);
        }
        __syncthreads();
    }

    // epilogue: C/D layout col=lane&15, row=quad*4+reg
    float* Cf = (float*)Cout + blockIdx.z * zstride;
    short* Cs = (short*)Cout;
#pragma unroll
    for (int mt = 0; mt < 4; mt++) {
#pragma unroll
        for (int nt = 0; nt < NT; nt++) {
            const size_t col = bn0 + wn + nt * 16 + l16;
            const float bc = bias ? bias[col] : 0.0f;
#pragma unroll
            for (int r = 0; r < 4; r++) {
                const size_t row = bm0 + wm + mt * 16 + quad * 4 + r;
                const float v = acc[mt][nt][r] * scale + bc;
                if (cmode == 1) {
                    Cf[row * (size_t)ldc + col] = v;
                } else if (cmode == 2) {
                    Cs[row * (size_t)ldc + col] = f2bf(__expf(v));
                } else {  // 5: q,k interleaved (ld 2048) + dense v
                    if (col < 2048) Cs[row * 2048 + col] = f2bf(v);
                    else            Vout[row * 1024 + (col - 2048)] = f2bf(v);
                }
            }
        }
    }
}

// 64x64 LDS-tiled transpose: vt[d][n] = v[n*1024 + d]
__global__ __launch_bounds__(256)
void transpose_v(const short* __restrict__ v, short* __restrict__ vt)
{
    __shared__ short sh[64][72];   // +8 pad
    const int n0 = blockIdx.x * 64, d0 = blockIdx.y * 64;
    const int t = threadIdx.x;
    const int r = t >> 2, c = (t & 3) << 4;

    const short* src = v + (size_t)(n0 + r) * 1024 + d0 + c;
    *(int4*)(&sh[r][c])     = *(const int4*)(src);
    *(int4*)(&sh[r][c + 8]) = *(const int4*)(src + 8);
    __syncthreads();

    short tmp[16];
#pragma unroll
    for (int j = 0; j < 16; j++) tmp[j] = sh[c + j][r];
    short* dst = vt + (size_t)(d0 + r) * 4096 + n0 + c;
    *(int4*)(dst)     = *(const int4*)(tmp);
    *(int4*)(dst + 8) = *(const int4*)(tmp + 8);
}

// One block per output row n: rsum = sum(E[n,:]);
// out[n,:] = (p0[n,:] + p1[n,:]) / rsum   (fp32 partials)
__global__ __launch_bounds__(256)
void reduce2div(const short* __restrict__ E, const float* __restrict__ outp,
                float* __restrict__ out)
{
    const int row = blockIdx.x;
    const int t = threadIdx.x;
    const int wave = t >> 6, lane = t & 63;

    const short* e = E + (size_t)row * 4096 + (t << 4);
    short sh[16];
    *(int4*)(sh)     = *(const int4*)(e);
    *(int4*)(sh + 8) = *(const int4*)(e + 8);
    float s = 0.0f;
#pragma unroll
    for (int i = 0; i < 16; i++) s += bf2f(sh[i]);
#pragma unroll
    for (int off = 32; off; off >>= 1) s += __shfl_down(s, off);
    __shared__ float red[4];
    if (lane == 0) red[wave] = s;
    __syncthreads();
    const float inv = 1.0f / (red[0] + red[1] + red[2] + red[3]);

    const size_t base = (size_t)row * 1024 + (t << 2);
    const float4 a = *(const float4*)(outp + base);
    const float4 b = *(const float4*)(outp + (size_t)4096 * 1024 + base);
    float4 o;
    o.x = (a.x + b.x) * inv; o.y = (a.y + b.y) * inv;
    o.z = (a.z + b.z) * inv; o.w = (a.w + b.w) * inv;
    *(float4*)(out + base) = o;
}

// single prep: x->xb, W1|W2|W3 -> Wb (element offsets!), bias concat
__global__ __launch_bounds__(256)
void prep(const float* __restrict__ x, const float* __restrict__ W1,
          const float* __restrict__ W2, const float* __restrict__ W3,
          const float* __restrict__ b1, const float* __restrict__ b2,
          const float* __restrict__ b3,
          short* __restrict__ xb, short* __restrict__ Wb,
          float* __restrict__ bcat)
{
    const int i = blockIdx.x * 256 + threadIdx.x;
    const int NX = 1048576;           // 4096*1024/4
    const int NW = 262144;            // 1024*1024/4
    if (i < NX + 3 * NW) {
        const float* src; short* dst; int j;
        if (i < NX)               { src = x;  dst = xb; j = i; }
        else if (i < NX + NW)     { src = W1; dst = Wb; j = i - NX; }
        else if (i < NX + 2 * NW) { src = W2; dst = Wb + 1048576; j = i - NX - NW; }
        else                      { src = W3; dst = Wb + 2097152; j = i - NX - 2 * NW; }
        const float4 f = ((const float4*)src)[j];
        short4 o;
        o.x = f2bf(f.x); o.y = f2bf(f.y); o.z = f2bf(f.z); o.w = f2bf(f.w);
        *(short4*)(dst + (j << 2)) = o;
    } else {
        const int j = i - (NX + 3 * NW);
        if (j < 3072)
            bcat[j] = (j < 1024) ? b1[j] : (j < 2048 ? b2[j - 1024] : b3[j - 2048]);
    }
}

extern "C" void kernel_launch(void* const* d_in, const int* in_sizes, int n_in,
                              void* d_out, int out_size, void* d_ws, size_t ws_size,
                              hipStream_t stream)
{
    const float* x  = (const float*)d_in[0];
    const float* W1 = (const float*)d_in[1];
    const float* b1 = (const float*)d_in[2];
    const float* W2 = (const float*)d_in[3];
    const float* b2 = (const float*)d_in[4];
    const float* W3 = (const float*)d_in[5];
    const float* b3 = (const float*)d_in[6];
    float* out = (float*)d_out;

    const int N = 4096, D = 1024;

    // workspace (peak 78 MB):
    //   vt   [0, 8M)      live: transpose .. out-gemm
    //   E    [8, 40M)     live: E-gemm .. reduce
    //   qk   [40, 56M)    interleaved q|k, ld 2048; dead after E-gemm
    //   v    [56, 64M)    dense; dead after transpose
    //   xb   [64, 72M)    dead after qkv-gemm
    //   Wb   [72, 78M)    dead after qkv-gemm
    //   bcat [78M, +12K)
    //   outp [40, 72M)    fp32 partials, overlays dead qk/v/xb
    char* wsb = (char*)d_ws;
    short* vt   = (short*)wsb;
    short* E    = (short*)(wsb + (size_t)8  * 1024 * 1024);
    short* qk   = (short*)(wsb + (size_t)40 * 1024 * 1024);  // 4096x2048 bf16
    short* v    = (short*)(wsb + (size_t)56 * 1024 * 1024);  // 4096x1024 bf16
    short* xb   = (short*)(wsb + (size_t)64 * 1024 * 1024);
    short* Wb   = (short*)(wsb + (size_t)72 * 1024 * 1024);
    float* bcat = (float*)(wsb + (size_t)78 * 1024 * 1024);
    float* outp = (float*)(wsb + (size_t)40 * 1024 * 1024);

    // 1) prep: casts + bias concat
    prep<<<(1048576 + 3 * 262144 + 3072 + 255) / 256, 256, 0, stream>>>(
        x, W1, W2, W3, b1, b2, b3, xb, Wb, bcat);

    // 2) qkv = x @ [W1;W2;W3]^T + bias -> qk interleaved + dense v
    //    (128x96, grid (32,32)=1024)
    dim3 gqkv(3 * D / 96, N / 128);
    gemm_bt<128, 96><<<gqkv, 256, 0, stream>>>(xb, D, Wb, D, bcat,
                                               qk, 0, 5, 1.0f, D, 0, v);

    // 3) vt[d][n] = v[n][d]   grid (64,16)=1024 blocks
    dim3 gt(N / 64, D / 64);
    transpose_v<<<gt, 256, 0, stream>>>(v, vt);

    // 4) E = exp((k q^T)/32) bf16  (128x128, grid 32x32; R4-layout operands)
    dim3 gs(N / 128, N / 128);
    gemm_bt<128, 128><<<gs, 256, 0, stream>>>(qk + D, 2 * D, qk, 2 * D,
                                              nullptr, E, N, 2, 0.03125f,
                                              D, 0, nullptr);

    // 5) out partials = E @ vt^T, split-K=2, fp32 (128x64, grid (16,32,2))
    dim3 go(D / 64, N / 128, 2);
    gemm_bt<128, 64><<<go, 256, 0, stream>>>(E, N, vt, N, nullptr,
                                             outp, D, 1, 1.0f, N / 2,
                                             (size_t)N * D, nullptr);

    // 6) out = (p0 + p1) / rowsum(E)
    reduce2div<<<N, 256, 0, stream>>>(E, outp, out);
}

// Round 11
// 247.976 us; speedup vs baseline: 1.0870x; 1.0516x over previous
//
#include <hip/hip_runtime.h>

// ---------------------------------------------------------------------------
// self_transformer: q=xW1^T+b1, k=xW2^T+b2, v=xW3^T+b3,
//                   attn=softmax((k q^T)/sqrt(D)), out=attn@v
// N=4096, D=1024. All matmuls via mfma_f32_16x16x32_bf16, fp32 accum.
// R11 = R10 + transpose_v fused into the qkv-gemm epilogue (cmode 6:
//     qk interleaved ld=2048, v written TRANSPOSED via short4 stores —
//     4 consecutive C-rows per lane = one 8B store). 5 launches total.
//     E-gemm operand layout (interleaved qk) is the R10-measured winner
//     (67 us vs 100 us dense: 8MiB-apart pow2-stride streams alias L2 sets).
// ---------------------------------------------------------------------------

typedef short bf16x8 __attribute__((ext_vector_type(8)));  // 8 bf16 = 4 VGPRs
typedef float f32x4  __attribute__((ext_vector_type(4)));

__device__ __forceinline__ short f2bf(float f) {
    unsigned u = __builtin_bit_cast(unsigned, f);
    u += 0x7FFFu + ((u >> 16) & 1u);   // round-to-nearest-even
    return (short)(u >> 16);
}
__device__ __forceinline__ float bf2f(short s) {
    return __builtin_bit_cast(float, (unsigned)((unsigned short)s) << 16);
}

__device__ __forceinline__ void gld_lds16(const short* g, short* l) {
    __builtin_amdgcn_global_load_lds(
        (const __attribute__((address_space(1))) void*)g,
        (__attribute__((address_space(3))) void*)l, 16, 0, 0);
}

// BT GEMM: C[a][b] = scale * sum_i A[a*lda+i] * B[b*ldb+i]  (+ per-col bias)
// cmode: 1 = fp32 store at split-K offset z*zstride (A/B k-offset z*K)
//        2 = bf16 exp() store (dense, ldc)
//        6 = qkv split: col<2048 -> Cs[row*2048+col] (qk interleaved);
//            col>=2048 -> Vt[(col-2048)*4096 + row] TRANSPOSED (short4 of
//            4 consecutive rows, C/D layout rows quad*4+0..3 are contiguous)
// LDS: BK=64, XOR-swizzled 16B granules: LDS granule p of row r holds global
// granule p^(r&7); fragment read granule (ks*4+quad)^(r&7) -> conflict-free.
template<int BM, int BN>
__global__ __launch_bounds__(256)
void gemm_bt(const short* __restrict__ A, int lda,
             const short* __restrict__ B, int ldb,
             const float* __restrict__ bias,
             void* __restrict__ Cout, int ldc, int cmode, float scale,
             int K, size_t zstride, short* __restrict__ Vt)
{
    constexpr int NT = BN / 32;                 // MFMA col-tiles per wave
    __shared__ __align__(16) short As[BM * 64];
    __shared__ __align__(16) short Bs[BN * 64];

    const int tid  = threadIdx.x;
    const int lane = tid & 63;
    const int wave = tid >> 6;
    const int wm   = (wave >> 1) * 64;          // wave row offset
    const int wn   = (wave & 1) * (BN / 2);     // wave col offset
    const int quad = lane >> 4;
    const int l16  = lane & 15;
    const size_t bm0 = (size_t)blockIdx.y * BM;
    const size_t bn0 = (size_t)blockIdx.x * BN;
    const int koff = blockIdx.z * K;

    f32x4 acc[4][NT] = {};

    // staging lane decode: chunk row + swizzled global granule
    const int srow = lane >> 3;                        // 0..7
    const int scol = ((lane & 7) ^ srow) << 3;         // swizzled elem col
    const short* Ag = A + (bm0 + srow) * (size_t)lda + koff + scol;
    const short* Bg = B + (bn0 + srow) * (size_t)ldb + koff + scol;

    for (int k0 = 0; k0 < K; k0 += 64) {
#pragma unroll
        for (int cc = 0; cc < BM / 8; cc += 4) {
            const int c = cc + wave;
            gld_lds16(Ag + (size_t)c * 8 * lda + k0, &As[c * 512]);
        }
#pragma unroll
        for (int cc = 0; cc < BN / 8; cc += 4) {
            const int c = cc + wave;
            gld_lds16(Bg + (size_t)c * 8 * ldb + k0, &Bs[c * 512]);
        }
        __syncthreads();

#pragma unroll
        for (int ks = 0; ks < 2; ks++) {
            const int sw = (ks << 2) + quad;
            bf16x8 af[4], bfr[NT];
#pragma unroll
            for (int mt = 0; mt < 4; mt++) {
                const int r = wm + mt * 16 + l16;
                af[mt] = *(const bf16x8*)(&As[r * 64 + ((sw ^ (r & 7)) << 3)]);
            }
#pragma unroll
            for (int nt = 0; nt < NT; nt++) {
                const int r = wn + nt * 16 + l16;
                bfr[nt] = *(const bf16x8*)(&Bs[r * 64 + ((sw ^ (r & 7)) << 3)]);
            }
#pragma unroll
            for (int mt = 0; mt < 4; mt++)
#pragma unroll
                for (int nt = 0; nt < NT; nt++)
                    acc[mt][nt] = __builtin_amdgcn_mfma_f32_16x16x32_bf16(
                        af[mt], bfr[nt], acc[mt][nt], 0, 0, 0);
        }
        __syncthreads();
    }

    // epilogue: C/D layout col=lane&15, row=quad*4+reg
    float* Cf = (float*)Cout + blockIdx.z * zstride;
    short* Cs = (short*)Cout;
#pragma unroll
    for (int mt = 0; mt < 4; mt++) {
#pragma unroll
        for (int nt = 0; nt < NT; nt++) {
            const size_t col = bn0 + wn + nt * 16 + l16;
            const float bc = bias ? bias[col] : 0.0f;
            if (cmode == 6 && col >= 2048) {
                // v: write transposed, 4 consecutive rows -> one short4
                short4 o;
#pragma unroll
                for (int r = 0; r < 4; r++)
                    ((short*)&o)[r] = f2bf(acc[mt][nt][r] * scale + bc);
                const size_t row0 = bm0 + wm + mt * 16 + quad * 4;
                *(short4*)(Vt + (col - 2048) * (size_t)4096 + row0) = o;
            } else {
#pragma unroll
                for (int r = 0; r < 4; r++) {
                    const size_t row = bm0 + wm + mt * 16 + quad * 4 + r;
                    const float v = acc[mt][nt][r] * scale + bc;
                    if (cmode == 1)      Cf[row * (size_t)ldc + col] = v;
                    else if (cmode == 2) Cs[row * (size_t)ldc + col] = f2bf(__expf(v));
                    else                 Cs[row * 2048 + col] = f2bf(v);  // 6: qk
                }
            }
        }
    }
}

// One block per output row n: rsum = sum(E[n,:]);
// out[n,:] = (p0[n,:] + p1[n,:]) / rsum   (fp32 partials)
__global__ __launch_bounds__(256)
void reduce2div(const short* __restrict__ E, const float* __restrict__ outp,
                float* __restrict__ out)
{
    const int row = blockIdx.x;
    const int t = threadIdx.x;
    const int wave = t >> 6, lane = t & 63;

    const short* e = E + (size_t)row * 4096 + (t << 4);
    short sh[16];
    *(int4*)(sh)     = *(const int4*)(e);
    *(int4*)(sh + 8) = *(const int4*)(e + 8);
    float s = 0.0f;
#pragma unroll
    for (int i = 0; i < 16; i++) s += bf2f(sh[i]);
#pragma unroll
    for (int off = 32; off; off >>= 1) s += __shfl_down(s, off);
    __shared__ float red[4];
    if (lane == 0) red[wave] = s;
    __syncthreads();
    const float inv = 1.0f / (red[0] + red[1] + red[2] + red[3]);

    const size_t base = (size_t)row * 1024 + (t << 2);
    const float4 a = *(const float4*)(outp + base);
    const float4 b = *(const float4*)(outp + (size_t)4096 * 1024 + base);
    float4 o;
    o.x = (a.x + b.x) * inv; o.y = (a.y + b.y) * inv;
    o.z = (a.z + b.z) * inv; o.w = (a.w + b.w) * inv;
    *(float4*)(out + base) = o;
}

// single prep: x->xb, W1|W2|W3 -> Wb (element offsets!), bias concat
__global__ __launch_bounds__(256)
void prep(const float* __restrict__ x, const float* __restrict__ W1,
          const float* __restrict__ W2, const float* __restrict__ W3,
          const float* __restrict__ b1, const float* __restrict__ b2,
          const float* __restrict__ b3,
          short* __restrict__ xb, short* __restrict__ Wb,
          float* __restrict__ bcat)
{
    const int i = blockIdx.x * 256 + threadIdx.x;
    const int NX = 1048576;           // 4096*1024/4
    const int NW = 262144;            // 1024*1024/4
    if (i < NX + 3 * NW) {
        const float* src; short* dst; int j;
        if (i < NX)               { src = x;  dst = xb; j = i; }
        else if (i < NX + NW)     { src = W1; dst = Wb; j = i - NX; }
        else if (i < NX + 2 * NW) { src = W2; dst = Wb + 1048576; j = i - NX - NW; }
        else                      { src = W3; dst = Wb + 2097152; j = i - NX - 2 * NW; }
        const float4 f = ((const float4*)src)[j];
        short4 o;
        o.x = f2bf(f.x); o.y = f2bf(f.y); o.z = f2bf(f.z); o.w = f2bf(f.w);
        *(short4*)(dst + (j << 2)) = o;
    } else {
        const int j = i - (NX + 3 * NW);
        if (j < 3072)
            bcat[j] = (j < 1024) ? b1[j] : (j < 2048 ? b2[j - 1024] : b3[j - 2048]);
    }
}

extern "C" void kernel_launch(void* const* d_in, const int* in_sizes, int n_in,
                              void* d_out, int out_size, void* d_ws, size_t ws_size,
                              hipStream_t stream)
{
    const float* x  = (const float*)d_in[0];
    const float* W1 = (const float*)d_in[1];
    const float* b1 = (const float*)d_in[2];
    const float* W2 = (const float*)d_in[3];
    const float* b2 = (const float*)d_in[4];
    const float* W3 = (const float*)d_in[5];
    const float* b3 = (const float*)d_in[6];
    float* out = (float*)d_out;

    const int N = 4096, D = 1024;

    // workspace (peak 78 MB):
    //   vt   [0, 8M)      live: qkv-gemm .. out-gemm (written by qkv epilogue)
    //   E    [8, 40M)     live: E-gemm .. reduce
    //   qk   [40, 56M)    interleaved q|k, ld 2048; dead after E-gemm
    //   xb   [64, 72M)    dead after qkv-gemm
    //   Wb   [72, 78M)    dead after qkv-gemm
    //   bcat [78M, +12K)
    //   outp [40, 72M)    fp32 partials, overlays dead qk/xb
    char* wsb = (char*)d_ws;
    short* vt   = (short*)wsb;
    short* E    = (short*)(wsb + (size_t)8  * 1024 * 1024);
    short* qk   = (short*)(wsb + (size_t)40 * 1024 * 1024);  // 4096x2048 bf16
    short* xb   = (short*)(wsb + (size_t)64 * 1024 * 1024);
    short* Wb   = (short*)(wsb + (size_t)72 * 1024 * 1024);
    float* bcat = (float*)(wsb + (size_t)78 * 1024 * 1024);
    float* outp = (float*)(wsb + (size_t)40 * 1024 * 1024);

    // 1) prep: casts + bias concat
    prep<<<(1048576 + 3 * 262144 + 3072 + 255) / 256, 256, 0, stream>>>(
        x, W1, W2, W3, b1, b2, b3, xb, Wb, bcat);

    // 2) qkv = x @ [W1;W2;W3]^T + bias -> qk interleaved + vt transposed
    //    (128x96, grid (32,32)=1024)
    dim3 gqkv(3 * D / 96, N / 128);
    gemm_bt<128, 96><<<gqkv, 256, 0, stream>>>(xb, D, Wb, D, bcat,
                                               qk, 0, 6, 1.0f, D, 0, vt);

    // 3) E = exp((k q^T)/32) bf16  (128x128, grid 32x32; interleaved operands)
    dim3 gs(N / 128, N / 128);
    gemm_bt<128, 128><<<gs, 256, 0, stream>>>(qk + D, 2 * D, qk, 2 * D,
                                              nullptr, E, N, 2, 0.03125f,
                                              D, 0, nullptr);

    // 4) out partials = E @ vt^T, split-K=2, fp32 (128x64, grid (16,32,2))
    dim3 go(D / 64, N / 128, 2);
    gemm_bt<128, 64><<<go, 256, 0, stream>>>(E, N, vt, N, nullptr,
                                             outp, D, 1, 1.0f, N / 2,
                                             (size_t)N * D, nullptr);

    // 5) out = (p0 + p1) / rowsum(E)
    reduce2div<<<N, 256, 0, stream>>>(E, outp, out);
}